// Round 1
// baseline (368.968 us; speedup 1.0000x reference)
//
#include <hip/hip_runtime.h>
#include <math.h>

#define NN 256
#define FEAT 1024
#define HIDR 256
#define HEADS 4
#define GCNH 256
#define M1 1024            // HEADS*GCNH
#define OUTC 21
#define MAXDEG (NN + 1)    // up to 256 topk-incoming + 1 self loop

// ---------------------------------------------------------------------------
// K1: A[i][k] = b_fc1[k] + feat[i]·Wa[:,k]   (Wa = W_fc1 rows 0..1023)
//     BT[k][j] = feat[j]·Wb[:,k]             (Wb = W_fc1 rows 1024..2047)
// B is stored transposed so the pair kernel reads it coalesced.
// grid 64 (32 A-blocks + 32 B-blocks), block 256, 8 rows per block.
__global__ __launch_bounds__(256) void k_gemmAB(
        const float* __restrict__ feat, const float* __restrict__ Wfc1,
        const float* __restrict__ bfc1, float* __restrict__ A,
        float* __restrict__ BT) {
    __shared__ float fS[8 * FEAT];
    int bid = blockIdx.x;
    bool isB = bid >= 32;
    int r0 = (isB ? bid - 32 : bid) * 8;
    int tid = threadIdx.x;
    for (int x = tid; x < 8 * FEAT; x += 256) fS[x] = feat[r0 * FEAT + x];
    __syncthreads();
    float acc[8];
#pragma unroll
    for (int r = 0; r < 8; r++) acc[r] = 0.f;
    const float* Wp = Wfc1 + (isB ? FEAT * HIDR : 0) + tid;
    for (int d = 0; d < FEAT; d++) {
        float w = Wp[(size_t)d * HIDR];
#pragma unroll
        for (int r = 0; r < 8; r++) acc[r] = fmaf(fS[r * FEAT + d], w, acc[r]);
    }
    if (!isB) {
        float b = bfc1[tid];
#pragma unroll
        for (int r = 0; r < 8; r++) A[(r0 + r) * HIDR + tid] = acc[r] + b;
    } else {
#pragma unroll
        for (int r = 0; r < 8; r++) BT[tid * NN + (r0 + r)] = acc[r];
    }
}

// ---------------------------------------------------------------------------
// K2: rel[i][j] = b_fc2 + sum_k relu(A[i,k] + BT[k,j] + g·Wg[:,k]) * W_fc2[k]
// grid 256 (i), block 256 (j).
__global__ __launch_bounds__(256) void k_rel(
        const float* __restrict__ A, const float* __restrict__ BT,
        const float* __restrict__ boxes, const float* __restrict__ Wfc1,
        const float* __restrict__ Wfc2, const float* __restrict__ bfc2,
        float* __restrict__ rel) {
    __shared__ float As[HIDR], w2[HIDR], wg[4][HIDR], bi[4];
    int i = blockIdx.x, j = threadIdx.x;
    As[j] = A[i * HIDR + j];
    w2[j] = Wfc2[j];
#pragma unroll
    for (int d = 0; d < 4; d++) wg[d][j] = Wfc1[(2 * FEAT + d) * HIDR + j];
    if (j < 4) bi[j] = boxes[i * 4 + j];
    __syncthreads();
    float g0 = fabsf(bi[0] - boxes[j * 4 + 0]);
    float g1 = fabsf(bi[1] - boxes[j * 4 + 1]);
    float g2 = fabsf(bi[2] - boxes[j * 4 + 2]);
    float g3 = fabsf(bi[3] - boxes[j * 4 + 3]);
    float acc = 0.f;
    for (int k = 0; k < HIDR; k++) {
        float v = As[k] + BT[k * NN + j];
        v = fmaf(g0, wg[0][k], v);
        v = fmaf(g1, wg[1][k], v);
        v = fmaf(g2, wg[2][k], v);
        v = fmaf(g3, wg[3][k], v);
        acc = fmaf(fmaxf(v, 0.f), w2[k], acc);
    }
    rel[i * NN + j] = acc + bfc2[0];
}

// ---------------------------------------------------------------------------
// K3: per-row top-4 (stable, lower index first on ties), keep ranks 1..3.
// Also computes normalized geometry node features. grid 1, block 256.
__global__ __launch_bounds__(256) void k_topk(
        const float* __restrict__ rel, const float* __restrict__ boxes,
        const int* __restrict__ imw, const int* __restrict__ imh,
        int* __restrict__ idxTop, float* __restrict__ geomn) {
    int i = threadIdx.x;
    float v0 = -1e38f, v1 = -1e38f, v2 = -1e38f, v3 = -1e38f;
    int i0 = -1, i1 = -1, i2 = -1, i3 = -1;
    const float* row = rel + i * NN;
    for (int j = 0; j < NN; j++) {
        float v = row[j];
        if (v > v3) {
            if (v > v0)      { v3=v2; i3=i2; v2=v1; i2=i1; v1=v0; i1=i0; v0=v; i0=j; }
            else if (v > v1) { v3=v2; i3=i2; v2=v1; i2=i1; v1=v;  i1=j; }
            else if (v > v2) { v3=v2; i3=i2; v2=v;  i2=j; }
            else             { v3=v;  i3=j; }
        }
    }
    idxTop[i * 3 + 0] = i1;
    idxTop[i * 3 + 1] = i2;
    idxTop[i * 3 + 2] = i3;
    float w = (float)imw[0], h = (float)imh[0];
    float x1 = boxes[i * 4 + 0] / w, y1 = boxes[i * 4 + 1] / h;
    float x2 = boxes[i * 4 + 2] / w, y2 = boxes[i * 4 + 3] / h;
    geomn[i * 4 + 0] = x1;
    geomn[i * 4 + 1] = y1;
    geomn[i * 4 + 2] = x2 - x1;
    geomn[i * 4 + 3] = y2 - y1;
}

// ---------------------------------------------------------------------------
// K4: deterministic incoming-edge lists per target (sources ascending, then
// the GATConv self loop). grid 1, block 256.
__global__ __launch_bounds__(256) void k_buildin(
        const int* __restrict__ idxTop, int* __restrict__ deg,
        int* __restrict__ inlist) {
    int t = threadIdx.x;
    int d = 0;
    for (int i = 0; i < NN; i++) {
#pragma unroll
        for (int k = 0; k < 3; k++)
            if (idxTop[i * 3 + k] == t) inlist[t * MAXDEG + (d++)] = i;
    }
    inlist[t * MAXDEG + (d++)] = t;  // self loop
    deg[t] = d;
}

// ---------------------------------------------------------------------------
// K5: hpre[n][m] = [feat[n], geomn[n]] @ W1   (256 x 1028 x 1024)
// grid (32,4), block 256, 8 rows x 256 cols per block.
__global__ __launch_bounds__(256) void k_gemm1(
        const float* __restrict__ feat, const float* __restrict__ geomn,
        const float* __restrict__ W1, float* __restrict__ hpre) {
    __shared__ float fS[8 * FEAT];
    __shared__ float gS[8 * 4];
    int r0 = blockIdx.x * 8;
    int c = blockIdx.y * 256 + threadIdx.x;
    int tid = threadIdx.x;
    for (int x = tid; x < 8 * FEAT; x += 256) fS[x] = feat[r0 * FEAT + x];
    if (tid < 32) gS[tid] = geomn[r0 * 4 + tid];
    __syncthreads();
    float acc[8];
#pragma unroll
    for (int r = 0; r < 8; r++) acc[r] = 0.f;
    for (int d = 0; d < FEAT; d++) {
        float w = W1[(size_t)d * M1 + c];
#pragma unroll
        for (int r = 0; r < 8; r++) acc[r] = fmaf(fS[r * FEAT + d], w, acc[r]);
    }
#pragma unroll
    for (int d = 0; d < 4; d++) {
        float w = W1[(size_t)(FEAT + d) * M1 + c];
#pragma unroll
        for (int r = 0; r < 8; r++) acc[r] = fmaf(gS[r * 4 + d], w, acc[r]);
    }
#pragma unroll
    for (int r = 0; r < 8; r++) hpre[(r0 + r) * M1 + c] = acc[r];
}

// ---------------------------------------------------------------------------
// K6: per-node, per-head attention dots es1/ed1. grid 256, block 256 (4 waves
// = 4 heads, 64-lane shuffle reduction).
__global__ __launch_bounds__(256) void k_scores1(
        const float* __restrict__ hpre, const float* __restrict__ as1,
        const float* __restrict__ ad1, float* __restrict__ es1,
        float* __restrict__ ed1) {
    int n = blockIdx.x;
    int h = threadIdx.x >> 6, l = threadIdx.x & 63;
    float ps = 0.f, pd = 0.f;
    for (int cc = l; cc < GCNH; cc += 64) {
        float x = hpre[n * M1 + h * GCNH + cc];
        ps = fmaf(x, as1[h * GCNH + cc], ps);
        pd = fmaf(x, ad1[h * GCNH + cc], pd);
    }
#pragma unroll
    for (int o = 32; o > 0; o >>= 1) {
        ps += __shfl_down(ps, o);
        pd += __shfl_down(pd, o);
    }
    if (l == 0) { es1[n * 4 + h] = ps; ed1[n * 4 + h] = pd; }
}

// ---------------------------------------------------------------------------
// K7: GAT layer 1 softmax-aggregate + bias + relu. grid 256 (target t),
// block 256; thread tid owns channels {q*256+tid} (head of that channel = q).
__global__ __launch_bounds__(256) void k_gat1(
        const float* __restrict__ hpre, const float* __restrict__ es1,
        const float* __restrict__ ed1, const int* __restrict__ deg,
        const int* __restrict__ inlist, const float* __restrict__ b1,
        float* __restrict__ h1) {
    __shared__ float sc[MAXDEG * 4];
    __shared__ float mh[4], dh[4];
    int t = blockIdx.x, tid = threadIdx.x;
    int dg = deg[t];
    for (int p = tid; p < dg * 4; p += 256) {
        int e = p >> 2, h = p & 3;
        int s = inlist[t * MAXDEG + e];
        float v = es1[s * 4 + h] + ed1[t * 4 + h];
        sc[p] = v >= 0.f ? v : 0.2f * v;  // leaky_relu(0.2)
    }
    __syncthreads();
    if (tid < 4) {
        float m = -1e30f;
        for (int e = 0; e < dg; e++) m = fmaxf(m, sc[e * 4 + tid]);
        float s = 0.f;
        for (int e = 0; e < dg; e++) s += expf(sc[e * 4 + tid] - m);
        mh[tid] = m; dh[tid] = s;
    }
    __syncthreads();
    for (int p = tid; p < dg * 4; p += 256) {
        int h = p & 3;
        sc[p] = expf(sc[p] - mh[h]) / dh[h];  // alpha
    }
    __syncthreads();
    float acc[4] = {0.f, 0.f, 0.f, 0.f};
    for (int e = 0; e < dg; e++) {
        int s = inlist[t * MAXDEG + e];
        const float* hs = hpre + (size_t)s * M1;
#pragma unroll
        for (int q = 0; q < 4; q++)
            acc[q] = fmaf(sc[e * 4 + q], hs[q * GCNH + tid], acc[q]);
    }
#pragma unroll
    for (int q = 0; q < 4; q++) {
        int c = q * GCNH + tid;
        h1[t * M1 + c] = fmaxf(acc[q] + b1[c], 0.f);
    }
}

// ---------------------------------------------------------------------------
// K8: h2 = h1 @ W2 (1024 -> 21), plus es2/ed2 dots. grid 256, block 64.
__global__ __launch_bounds__(64) void k_h2(
        const float* __restrict__ h1, const float* __restrict__ W2,
        const float* __restrict__ as2, const float* __restrict__ ad2,
        float* __restrict__ h2, float* __restrict__ es2,
        float* __restrict__ ed2) {
    __shared__ float hv[OUTC];
    int n = blockIdx.x, o = threadIdx.x;
    if (o < OUTC) {
        float acc = 0.f;
        for (int d = 0; d < M1; d++)
            acc = fmaf(h1[n * M1 + d], W2[d * OUTC + o], acc);
        h2[n * OUTC + o] = acc;
        hv[o] = acc;
    }
    __syncthreads();
    if (o == 0) {
        float s = 0.f, dd = 0.f;
        for (int k = 0; k < OUTC; k++) {
            s = fmaf(hv[k], as2[k], s);
            dd = fmaf(hv[k], ad2[k], dd);
        }
        es2[n] = s; ed2[n] = dd;
    }
}

// ---------------------------------------------------------------------------
// K9: GAT layer 2 softmax-aggregate + bias -> logits; argmax -> labels.
// grid 256 (target t), block 64. out = [logits (256x21) | labels (256) as f32]
__global__ __launch_bounds__(64) void k_gat2(
        const float* __restrict__ h2, const float* __restrict__ es2,
        const float* __restrict__ ed2, const int* __restrict__ deg,
        const int* __restrict__ inlist, const float* __restrict__ b2,
        float* __restrict__ out) {
    __shared__ float sc[MAXDEG];
    __shared__ float md[2];
    __shared__ float lv[OUTC];
    int t = blockIdx.x, tid = threadIdx.x;
    int dg = deg[t];
    float edt = ed2[t];
    for (int p = tid; p < dg; p += 64) {
        int s = inlist[t * MAXDEG + p];
        float v = es2[s] + edt;
        sc[p] = v >= 0.f ? v : 0.2f * v;
    }
    __syncthreads();
    if (tid == 0) {
        float m = -1e30f;
        for (int e = 0; e < dg; e++) m = fmaxf(m, sc[e]);
        float s = 0.f;
        for (int e = 0; e < dg; e++) s += expf(sc[e] - m);
        md[0] = m; md[1] = s;
    }
    __syncthreads();
    if (tid < OUTC) {
        float acc = 0.f;
        for (int e = 0; e < dg; e++) {
            int s = inlist[t * MAXDEG + e];
            float a = expf(sc[e] - md[0]) / md[1];
            acc = fmaf(a, h2[s * OUTC + tid], acc);
        }
        float v = acc + b2[tid];
        out[t * OUTC + tid] = v;
        lv[tid] = v;
    }
    __syncthreads();
    if (tid == 0) {
        int best = 0;
        float bv = lv[0];
        for (int o = 1; o < OUTC; o++)
            if (lv[o] > bv) { bv = lv[o]; best = o; }  // first max wins
        out[NN * OUTC + t] = (float)best;
    }
}

// ---------------------------------------------------------------------------
extern "C" void kernel_launch(void* const* d_in, const int* in_sizes, int n_in,
                              void* d_out, int out_size, void* d_ws,
                              size_t ws_size, hipStream_t stream) {
    const float* feat  = (const float*)d_in[0];
    const float* boxes = (const float*)d_in[1];
    const float* Wfc1  = (const float*)d_in[2];
    const float* bfc1  = (const float*)d_in[3];
    const float* Wfc2  = (const float*)d_in[4];
    const float* bfc2  = (const float*)d_in[5];
    const float* W1    = (const float*)d_in[6];
    const float* as1   = (const float*)d_in[7];
    const float* ad1   = (const float*)d_in[8];
    const float* b1    = (const float*)d_in[9];
    const float* W2    = (const float*)d_in[10];
    const float* as2   = (const float*)d_in[11];
    const float* ad2   = (const float*)d_in[12];
    const float* b2    = (const float*)d_in[13];
    const int*   imh   = (const int*)d_in[14];
    const int*   imw   = (const int*)d_in[15];

    float* ws = (float*)d_ws;
    float* A     = ws;  ws += NN * HIDR;
    float* BT    = ws;  ws += NN * HIDR;
    float* rel   = ws;  ws += NN * NN;
    float* hpre  = ws;  ws += NN * M1;
    float* h1    = ws;  ws += NN * M1;
    float* es1   = ws;  ws += NN * 4;
    float* ed1   = ws;  ws += NN * 4;
    float* h2    = ws;  ws += NN * OUTC;
    float* es2   = ws;  ws += NN;
    float* ed2   = ws;  ws += NN;
    float* geomn = ws;  ws += NN * 4;
    int* idxTop  = (int*)ws;
    int* deg     = idxTop + NN * 3;
    int* inlist  = deg + NN;

    float* out = (float*)d_out;

    k_gemmAB<<<64, 256, 0, stream>>>(feat, Wfc1, bfc1, A, BT);
    k_rel<<<NN, 256, 0, stream>>>(A, BT, boxes, Wfc1, Wfc2, bfc2, rel);
    k_topk<<<1, 256, 0, stream>>>(rel, boxes, imw, imh, idxTop, geomn);
    k_buildin<<<1, 256, 0, stream>>>(idxTop, deg, inlist);
    k_gemm1<<<dim3(32, 4), 256, 0, stream>>>(feat, geomn, W1, hpre);
    k_scores1<<<NN, 256, 0, stream>>>(hpre, as1, ad1, es1, ed1);
    k_gat1<<<NN, 256, 0, stream>>>(hpre, es1, ed1, deg, inlist, b1, h1);
    k_h2<<<NN, 64, 0, stream>>>(h1, W2, as2, ad2, h2, es2, ed2);
    k_gat2<<<NN, 64, 0, stream>>>(h2, es2, ed2, deg, inlist, b2, out);
}

// Round 2
// 249.040 us; speedup vs baseline: 1.4816x; 1.4816x over previous
//
#include <hip/hip_runtime.h>
#include <math.h>

#define NN 256
#define FEAT 1024
#define HIDR 256
#define HEADS 4
#define GCNH 256
#define M1 1024            // HEADS*GCNH
#define OUTC 21
#define MAXDEG (NN + 1)    // up to 256 topk-incoming + 1 self loop
#define KC 4               // split-K factor for the fused GEMM
#define KCH (FEAT / KC)    // 256
#define FCOLS 1536         // fused output cols: A(256) | B(256) | hpre(1024)

// ---------------------------------------------------------------------------
// K1: fused split-K GEMM. Output cols [0,256)=A pre-bias, [256,512)=B,
// [512,1536)=feat@W1[:1024] (hpre without the geom rows, added later).
// grid (32 row-groups, 3 col-groups of 512, 4 K-chunks), block 256.
// Each thread owns 2 consecutive cols (float2 W loads), 8 rows.
__global__ __launch_bounds__(256) void k_big(
        const float* __restrict__ feat, const float* __restrict__ Wfc1,
        const float* __restrict__ W1, float* __restrict__ P) {
    __shared__ float fS[8][KCH];
    int rg = blockIdx.x, cg = blockIdx.y, kc = blockIdx.z;
    int tid = threadIdx.x;
    int r0 = rg * 8, k0 = kc * KCH;
    for (int x = tid; x < 8 * KCH; x += 256) {
        int r = x >> 8, kk = x & (KCH - 1);
        fS[r][kk] = feat[(size_t)(r0 + r) * FEAT + k0 + kk];
    }
    __syncthreads();
    int gc = cg * 512 + tid * 2;
    const float* pW;
    int ld;
    if (gc < 256)      { pW = Wfc1 + (size_t)k0 * HIDR + gc;                  ld = HIDR; }
    else if (gc < 512) { pW = Wfc1 + (size_t)(FEAT + k0) * HIDR + (gc - 256); ld = HIDR; }
    else               { pW = W1   + (size_t)k0 * M1 + (gc - 512);            ld = M1;   }
    float2 acc[8];
#pragma unroll
    for (int r = 0; r < 8; r++) { acc[r].x = 0.f; acc[r].y = 0.f; }
    for (int kk = 0; kk < KCH; kk += 4) {
        float2 w0 = *(const float2*)(pW);
        float2 w1 = *(const float2*)(pW + ld);
        float2 w2 = *(const float2*)(pW + 2 * ld);
        float2 w3 = *(const float2*)(pW + 3 * ld);
        pW += 4 * ld;
#pragma unroll
        for (int r = 0; r < 8; r++) {
            float4 f = *(const float4*)&fS[r][kk];
            acc[r].x = fmaf(f.x, w0.x, acc[r].x); acc[r].y = fmaf(f.x, w0.y, acc[r].y);
            acc[r].x = fmaf(f.y, w1.x, acc[r].x); acc[r].y = fmaf(f.y, w1.y, acc[r].y);
            acc[r].x = fmaf(f.z, w2.x, acc[r].x); acc[r].y = fmaf(f.z, w2.y, acc[r].y);
            acc[r].x = fmaf(f.w, w3.x, acc[r].x); acc[r].y = fmaf(f.w, w3.y, acc[r].y);
        }
    }
    float* Pp = P + ((size_t)kc * NN + r0) * FCOLS + gc;
#pragma unroll
    for (int r = 0; r < 8; r++)
        *(float2*)(Pp + (size_t)r * FCOLS) = acc[r];
}

// ---------------------------------------------------------------------------
// K2: reduce 4 split-K partials; route to A (+bias), BT (transposed), hpre.
// grid 384, block 256: one float4 of the 256x1536 fused matrix per thread.
__global__ __launch_bounds__(256) void k_reduce(
        const float* __restrict__ P, const float* __restrict__ bfc1,
        float* __restrict__ A, float* __restrict__ BT,
        float* __restrict__ hpre) {
    int t = blockIdx.x * 256 + threadIdx.x;
    int row = t / (FCOLS / 4);
    int c4 = (t - row * (FCOLS / 4)) * 4;
    const float* p = P + (size_t)row * FCOLS + c4;
    const size_t str = (size_t)NN * FCOLS;
    float4 s0 = *(const float4*)p;
    float4 s1 = *(const float4*)(p + str);
    float4 s2 = *(const float4*)(p + 2 * str);
    float4 s3 = *(const float4*)(p + 3 * str);
    float4 s;
    s.x = (s0.x + s1.x) + (s2.x + s3.x);
    s.y = (s0.y + s1.y) + (s2.y + s3.y);
    s.z = (s0.z + s1.z) + (s2.z + s3.z);
    s.w = (s0.w + s1.w) + (s2.w + s3.w);
    if (c4 < 256) {
        float4 b = *(const float4*)(bfc1 + c4);
        s.x += b.x; s.y += b.y; s.z += b.z; s.w += b.w;
        *(float4*)(A + (size_t)row * HIDR + c4) = s;
    } else if (c4 < 512) {
        int kk = c4 - 256;
        BT[(kk + 0) * NN + row] = s.x;
        BT[(kk + 1) * NN + row] = s.y;
        BT[(kk + 2) * NN + row] = s.z;
        BT[(kk + 3) * NN + row] = s.w;
    } else {
        *(float4*)(hpre + (size_t)row * M1 + (c4 - 512)) = s;
    }
}

// ---------------------------------------------------------------------------
// K3: rel partials, split-K=2. relp[kc][i][j] = sum_{k in chunk}
//   relu(A[i,k] + BT[k,j] + g_ij·Wg[:,k]) * W_fc2[k].  (b_fc2 dropped: a
// constant shift cannot change top-k order and rel is not an output.)
// grid (256, 2), block 256.
__global__ __launch_bounds__(256) void k_rel2(
        const float* __restrict__ A, const float* __restrict__ BT,
        const float* __restrict__ boxes, const float* __restrict__ Wfc1,
        const float* __restrict__ Wfc2, float* __restrict__ relp) {
    __shared__ float As[128], w2s[128], wg0[128], wg1[128], wg2[128], wg3[128];
    int i = blockIdx.x, kc = blockIdx.y, k0 = kc * 128;
    int j = threadIdx.x;
    if (j < 128) {
        As[j]  = A[i * HIDR + k0 + j];
        w2s[j] = Wfc2[k0 + j];
        wg0[j] = Wfc1[(size_t)(2 * FEAT + 0) * HIDR + k0 + j];
        wg1[j] = Wfc1[(size_t)(2 * FEAT + 1) * HIDR + k0 + j];
        wg2[j] = Wfc1[(size_t)(2 * FEAT + 2) * HIDR + k0 + j];
        wg3[j] = Wfc1[(size_t)(2 * FEAT + 3) * HIDR + k0 + j];
    }
    float bi0 = boxes[i * 4 + 0], bi1 = boxes[i * 4 + 1];
    float bi2 = boxes[i * 4 + 2], bi3 = boxes[i * 4 + 3];
    __syncthreads();
    float g0 = fabsf(bi0 - boxes[j * 4 + 0]);
    float g1 = fabsf(bi1 - boxes[j * 4 + 1]);
    float g2 = fabsf(bi2 - boxes[j * 4 + 2]);
    float g3 = fabsf(bi3 - boxes[j * 4 + 3]);
    const float* pB = BT + (size_t)k0 * NN + j;
    float acc = 0.f;
    for (int kk = 0; kk < 128; kk += 4) {
        float4 a4 = *(const float4*)&As[kk];
        float4 w4 = *(const float4*)&w2s[kk];
        float4 q0 = *(const float4*)&wg0[kk];
        float4 q1 = *(const float4*)&wg1[kk];
        float4 q2 = *(const float4*)&wg2[kk];
        float4 q3 = *(const float4*)&wg3[kk];
        float b0 = pB[0], b1 = pB[NN], b2 = pB[2 * NN], b3 = pB[3 * NN];
        pB += 4 * NN;
        float v;
        v = a4.x + b0; v = fmaf(g0, q0.x, v); v = fmaf(g1, q1.x, v);
        v = fmaf(g2, q2.x, v); v = fmaf(g3, q3.x, v);
        acc = fmaf(fmaxf(v, 0.f), w4.x, acc);
        v = a4.y + b1; v = fmaf(g0, q0.y, v); v = fmaf(g1, q1.y, v);
        v = fmaf(g2, q2.y, v); v = fmaf(g3, q3.y, v);
        acc = fmaf(fmaxf(v, 0.f), w4.y, acc);
        v = a4.z + b2; v = fmaf(g0, q0.z, v); v = fmaf(g1, q1.z, v);
        v = fmaf(g2, q2.z, v); v = fmaf(g3, q3.z, v);
        acc = fmaf(fmaxf(v, 0.f), w4.z, acc);
        v = a4.w + b3; v = fmaf(g0, q0.w, v); v = fmaf(g1, q1.w, v);
        v = fmaf(g2, q2.w, v); v = fmaf(g3, q3.w, v);
        acc = fmaf(fmaxf(v, 0.f), w4.w, acc);
    }
    relp[((size_t)kc * NN + i) * NN + j] = acc;
}

// ---------------------------------------------------------------------------
// K4: fused top-k + geomn + incoming-edge-list build. grid 1, block 256.
// Thread i: sums the two rel partials on the fly, tracks top-4 (stable:
// strict > keeps lower index first on ties), drops rank 0. Then all threads
// cooperatively build per-target lists via LDS atomic slots (+ self loop).
__global__ __launch_bounds__(256) void k_topk_build(
        const float* __restrict__ relp, const float* __restrict__ boxes,
        const int* __restrict__ imh, const int* __restrict__ imw,
        float* __restrict__ geomn, int* __restrict__ deg,
        int* __restrict__ inlist) {
    __shared__ int sidx[NN * 3];
    __shared__ int degL[NN];
    int i = threadIdx.x;
    degL[i] = 0;
    const float* r0p = relp + (size_t)i * NN;
    const float* r1p = relp + (size_t)(NN + i) * NN;
    float v0 = -1e38f, v1 = -1e38f, v2 = -1e38f, v3 = -1e38f;
    int i0 = -1, i1 = -1, i2 = -1, i3 = -1;
    for (int j = 0; j < NN; j++) {
        float v = r0p[j] + r1p[j];
        if (v > v3) {
            if (v > v0)      { v3=v2; i3=i2; v2=v1; i2=i1; v1=v0; i1=i0; v0=v; i0=j; }
            else if (v > v1) { v3=v2; i3=i2; v2=v1; i2=i1; v1=v;  i1=j; }
            else if (v > v2) { v3=v2; i3=i2; v2=v;  i2=j; }
            else             { v3=v;  i3=j; }
        }
    }
    sidx[i * 3 + 0] = i1;
    sidx[i * 3 + 1] = i2;
    sidx[i * 3 + 2] = i3;
    float w = (float)imw[0], h = (float)imh[0];
    float x1 = boxes[i * 4 + 0] / w, y1 = boxes[i * 4 + 1] / h;
    float x2 = boxes[i * 4 + 2] / w, y2 = boxes[i * 4 + 3] / h;
    geomn[i * 4 + 0] = x1;
    geomn[i * 4 + 1] = y1;
    geomn[i * 4 + 2] = x2 - x1;
    geomn[i * 4 + 3] = y2 - y1;
    __syncthreads();
#pragma unroll
    for (int k = 0; k < 3; k++) {
        int t = sidx[i * 3 + k];
        int slot = atomicAdd(&degL[t], 1);
        inlist[t * MAXDEG + slot] = i;
    }
    __syncthreads();
    int d = degL[i];
    inlist[i * MAXDEG + d] = i;   // GATConv self loop
    deg[i] = d + 1;
}

// ---------------------------------------------------------------------------
// K5: add geomn contribution to hpre (the deferred W1 rows 1024..1027) and
// compute per-node, per-head attention dots es1/ed1. grid 256 (node n),
// block 256: thread owns 4 consecutive channels; wave w == head w.
__global__ __launch_bounds__(256) void k_fixscore(
        float* __restrict__ hpre, const float* __restrict__ geomn,
        const float* __restrict__ W1, const float* __restrict__ as1,
        const float* __restrict__ ad1, float* __restrict__ es1,
        float* __restrict__ ed1) {
    int n = blockIdx.x, tid = threadIdx.x;
    int c = tid * 4;
    float g0 = geomn[n * 4 + 0], g1 = geomn[n * 4 + 1];
    float g2 = geomn[n * 4 + 2], g3 = geomn[n * 4 + 3];
    float4 hx = *(const float4*)(hpre + (size_t)n * M1 + c);
    float4 wv;
    wv = *(const float4*)(W1 + (size_t)(FEAT + 0) * M1 + c);
    hx.x = fmaf(g0, wv.x, hx.x); hx.y = fmaf(g0, wv.y, hx.y);
    hx.z = fmaf(g0, wv.z, hx.z); hx.w = fmaf(g0, wv.w, hx.w);
    wv = *(const float4*)(W1 + (size_t)(FEAT + 1) * M1 + c);
    hx.x = fmaf(g1, wv.x, hx.x); hx.y = fmaf(g1, wv.y, hx.y);
    hx.z = fmaf(g1, wv.z, hx.z); hx.w = fmaf(g1, wv.w, hx.w);
    wv = *(const float4*)(W1 + (size_t)(FEAT + 2) * M1 + c);
    hx.x = fmaf(g2, wv.x, hx.x); hx.y = fmaf(g2, wv.y, hx.y);
    hx.z = fmaf(g2, wv.z, hx.z); hx.w = fmaf(g2, wv.w, hx.w);
    wv = *(const float4*)(W1 + (size_t)(FEAT + 3) * M1 + c);
    hx.x = fmaf(g3, wv.x, hx.x); hx.y = fmaf(g3, wv.y, hx.y);
    hx.z = fmaf(g3, wv.z, hx.z); hx.w = fmaf(g3, wv.w, hx.w);
    *(float4*)(hpre + (size_t)n * M1 + c) = hx;
    float4 a = *(const float4*)(as1 + c);
    float4 b = *(const float4*)(ad1 + c);
    float ps = hx.x * a.x + hx.y * a.y + hx.z * a.z + hx.w * a.w;
    float pd = hx.x * b.x + hx.y * b.y + hx.z * b.z + hx.w * b.w;
#pragma unroll
    for (int o = 32; o > 0; o >>= 1) {
        ps += __shfl_down(ps, o);
        pd += __shfl_down(pd, o);
    }
    if ((tid & 63) == 0) {
        es1[n * 4 + (tid >> 6)] = ps;
        ed1[n * 4 + (tid >> 6)] = pd;
    }
}

// ---------------------------------------------------------------------------
// K6: GAT layer 1 softmax-aggregate + bias + relu. grid 256 (target t),
// block 256; thread tid owns channels {q*256+tid}.
__global__ __launch_bounds__(256) void k_gat1(
        const float* __restrict__ hpre, const float* __restrict__ es1,
        const float* __restrict__ ed1, const int* __restrict__ deg,
        const int* __restrict__ inlist, const float* __restrict__ b1,
        float* __restrict__ h1) {
    __shared__ float sc[MAXDEG * 4];
    __shared__ float mh[4], dh[4];
    int t = blockIdx.x, tid = threadIdx.x;
    int dg = deg[t];
    for (int p = tid; p < dg * 4; p += 256) {
        int e = p >> 2, h = p & 3;
        int s = inlist[t * MAXDEG + e];
        float v = es1[s * 4 + h] + ed1[t * 4 + h];
        sc[p] = v >= 0.f ? v : 0.2f * v;  // leaky_relu(0.2)
    }
    __syncthreads();
    if (tid < 4) {
        float m = -1e30f;
        for (int e = 0; e < dg; e++) m = fmaxf(m, sc[e * 4 + tid]);
        float s = 0.f;
        for (int e = 0; e < dg; e++) s += expf(sc[e * 4 + tid] - m);
        mh[tid] = m; dh[tid] = s;
    }
    __syncthreads();
    for (int p = tid; p < dg * 4; p += 256) {
        int h = p & 3;
        sc[p] = expf(sc[p] - mh[h]) / dh[h];  // alpha
    }
    __syncthreads();
    float acc[4] = {0.f, 0.f, 0.f, 0.f};
    for (int e = 0; e < dg; e++) {
        int s = inlist[t * MAXDEG + e];
        const float* hs = hpre + (size_t)s * M1;
#pragma unroll
        for (int q = 0; q < 4; q++)
            acc[q] = fmaf(sc[e * 4 + q], hs[q * GCNH + tid], acc[q]);
    }
#pragma unroll
    for (int q = 0; q < 4; q++) {
        int c = q * GCNH + tid;
        h1[(size_t)t * M1 + c] = fmaxf(acc[q] + b1[c], 0.f);
    }
}

// ---------------------------------------------------------------------------
// K7: h2 = h1 @ W2 (1024 -> 21) + es2/ed2 dots. grid 256, block 256.
// Threads (o,p) with o=tid%21, p=tid/21 (252 active): coalesced W2 reads.
__global__ __launch_bounds__(256) void k_h2(
        const float* __restrict__ h1, const float* __restrict__ W2,
        const float* __restrict__ as2, const float* __restrict__ ad2,
        float* __restrict__ h2, float* __restrict__ es2,
        float* __restrict__ ed2) {
    __shared__ float sh[M1];
    __shared__ float part[12 * OUTC];
    __shared__ float h2row[OUTC];
    int n = blockIdx.x, tid = threadIdx.x;
    *(float4*)&sh[tid * 4] = *(const float4*)(h1 + (size_t)n * M1 + tid * 4);
    __syncthreads();
    if (tid < 252) {
        int o = tid % OUTC, p = tid / OUTC;
        float acc = 0.f;
        for (int d = p; d < M1; d += 12)
            acc = fmaf(sh[d], W2[d * OUTC + o], acc);
        part[p * OUTC + o] = acc;
    }
    __syncthreads();
    if (tid < OUTC) {
        float s = 0.f;
        for (int p = 0; p < 12; p++) s += part[p * OUTC + tid];
        h2[n * OUTC + tid] = s;
        h2row[tid] = s;
    }
    __syncthreads();
    if (tid == 0) {
        float s = 0.f, dd = 0.f;
        for (int k = 0; k < OUTC; k++) {
            s = fmaf(h2row[k], as2[k], s);
            dd = fmaf(h2row[k], ad2[k], dd);
        }
        es2[n] = s; ed2[n] = dd;
    }
}

// ---------------------------------------------------------------------------
// K8: GAT layer 2 softmax-aggregate + bias -> logits; argmax -> labels.
// grid 256 (target t), block 64. out = [logits (256x21) | labels (256) as f32]
__global__ __launch_bounds__(64) void k_gat2(
        const float* __restrict__ h2, const float* __restrict__ es2,
        const float* __restrict__ ed2, const int* __restrict__ deg,
        const int* __restrict__ inlist, const float* __restrict__ b2,
        float* __restrict__ out) {
    __shared__ float sc[MAXDEG];
    __shared__ float md[2];
    __shared__ float lv[OUTC];
    int t = blockIdx.x, tid = threadIdx.x;
    int dg = deg[t];
    float edt = ed2[t];
    for (int p = tid; p < dg; p += 64) {
        int s = inlist[t * MAXDEG + p];
        float v = es2[s] + edt;
        sc[p] = v >= 0.f ? v : 0.2f * v;
    }
    __syncthreads();
    if (tid == 0) {
        float m = -1e30f;
        for (int e = 0; e < dg; e++) m = fmaxf(m, sc[e]);
        float s = 0.f;
        for (int e = 0; e < dg; e++) s += expf(sc[e] - m);
        md[0] = m; md[1] = s;
    }
    __syncthreads();
    if (tid < OUTC) {
        float acc = 0.f;
        for (int e = 0; e < dg; e++) {
            int s = inlist[t * MAXDEG + e];
            float a = expf(sc[e] - md[0]) / md[1];
            acc = fmaf(a, h2[s * OUTC + tid], acc);
        }
        float v = acc + b2[tid];
        out[t * OUTC + tid] = v;
        lv[tid] = v;
    }
    __syncthreads();
    if (tid == 0) {
        int best = 0;
        float bv = lv[0];
        for (int o = 1; o < OUTC; o++)
            if (lv[o] > bv) { bv = lv[o]; best = o; }  // first max wins
        out[NN * OUTC + t] = (float)best;
    }
}

// ---------------------------------------------------------------------------
extern "C" void kernel_launch(void* const* d_in, const int* in_sizes, int n_in,
                              void* d_out, int out_size, void* d_ws,
                              size_t ws_size, hipStream_t stream) {
    const float* feat  = (const float*)d_in[0];
    const float* boxes = (const float*)d_in[1];
    const float* Wfc1  = (const float*)d_in[2];
    const float* bfc1  = (const float*)d_in[3];
    const float* Wfc2  = (const float*)d_in[4];
    const float* bfc2  = (const float*)d_in[5];   (void)bfc2;
    const float* W1    = (const float*)d_in[6];
    const float* as1   = (const float*)d_in[7];
    const float* ad1   = (const float*)d_in[8];
    const float* b1    = (const float*)d_in[9];
    const float* W2    = (const float*)d_in[10];
    const float* as2   = (const float*)d_in[11];
    const float* ad2   = (const float*)d_in[12];
    const float* b2    = (const float*)d_in[13];
    const int*   imh   = (const int*)d_in[14];
    const int*   imw   = (const int*)d_in[15];

    float* ws = (float*)d_ws;
    float* P     = ws;  ws += KC * NN * FCOLS;   // 1,572,864
    float* A     = ws;  ws += NN * HIDR;
    float* BT    = ws;  ws += NN * HIDR;
    float* hpre  = ws;  ws += NN * M1;
    float* relp  = ws;  ws += 2 * NN * NN;
    float* h1    = ws;  ws += NN * M1;
    float* es1   = ws;  ws += NN * 4;
    float* ed1   = ws;  ws += NN * 4;
    float* h2    = ws;  ws += NN * OUTC;
    float* es2   = ws;  ws += NN;
    float* ed2   = ws;  ws += NN;
    float* geomn = ws;  ws += NN * 4;
    int* deg     = (int*)ws;
    int* inlist  = deg + NN;

    float* out = (float*)d_out;

    k_big<<<dim3(32, 3, KC), 256, 0, stream>>>(feat, Wfc1, W1, P);
    k_reduce<<<384, 256, 0, stream>>>(P, bfc1, A, BT, hpre);
    k_rel2<<<dim3(NN, 2), 256, 0, stream>>>(A, BT, boxes, Wfc1, Wfc2, relp);
    k_topk_build<<<1, 256, 0, stream>>>(relp, boxes, imh, imw, geomn, deg, inlist);
    k_fixscore<<<NN, 256, 0, stream>>>(hpre, geomn, W1, as1, ad1, es1, ed1);
    k_gat1<<<NN, 256, 0, stream>>>(hpre, es1, ed1, deg, inlist, b1, h1);
    k_h2<<<NN, 256, 0, stream>>>(h1, W2, as2, ad2, h2, es2, ed2);
    k_gat2<<<NN, 64, 0, stream>>>(h2, es2, ed2, deg, inlist, b2, out);
}

// Round 3
// 187.944 us; speedup vs baseline: 1.9632x; 1.3251x over previous
//
#include <hip/hip_runtime.h>
#include <math.h>

#define NN 256
#define FEAT 1024
#define HIDR 256
#define HEADS 4
#define GCNH 256
#define M1 1024            // HEADS*GCNH
#define OUTC 21
#define MAXDEG (NN + 1)    // up to 256 topk-incoming + 1 self loop
#define KC 4               // split-K factor for the fused GEMM
#define KCH (FEAT / KC)    // 256
#define FCOLS 1536         // fused output cols: A(256) | B(256) | hpre(1024)
#define KR 4               // split-K factor for rel
#define KRC (HIDR / KR)    // 64

// ---------------------------------------------------------------------------
// K1: fused split-K GEMM. Output cols [0,256)=A pre-bias, [256,512)=B,
// [512,1536)=feat@W1[:1024] (hpre without the geom rows, added later).
// grid (32 row-groups, 3 col-groups of 512, 4 K-chunks), block 256.
__global__ __launch_bounds__(256) void k_big(
        const float* __restrict__ feat, const float* __restrict__ Wfc1,
        const float* __restrict__ W1, float* __restrict__ P) {
    __shared__ float fS[8][KCH];
    int rg = blockIdx.x, cg = blockIdx.y, kc = blockIdx.z;
    int tid = threadIdx.x;
    int r0 = rg * 8, k0 = kc * KCH;
    for (int x = tid; x < 8 * KCH; x += 256) {
        int r = x >> 8, kk = x & (KCH - 1);
        fS[r][kk] = feat[(size_t)(r0 + r) * FEAT + k0 + kk];
    }
    __syncthreads();
    int gc = cg * 512 + tid * 2;
    const float* pW;
    int ld;
    if (gc < 256)      { pW = Wfc1 + (size_t)k0 * HIDR + gc;                  ld = HIDR; }
    else if (gc < 512) { pW = Wfc1 + (size_t)(FEAT + k0) * HIDR + (gc - 256); ld = HIDR; }
    else               { pW = W1   + (size_t)k0 * M1 + (gc - 512);            ld = M1;   }
    float2 acc[8];
#pragma unroll
    for (int r = 0; r < 8; r++) { acc[r].x = 0.f; acc[r].y = 0.f; }
    for (int kk = 0; kk < KCH; kk += 4) {
        float2 w0 = *(const float2*)(pW);
        float2 w1 = *(const float2*)(pW + ld);
        float2 w2 = *(const float2*)(pW + 2 * ld);
        float2 w3 = *(const float2*)(pW + 3 * ld);
        pW += 4 * ld;
#pragma unroll
        for (int r = 0; r < 8; r++) {
            float4 f = *(const float4*)&fS[r][kk];
            acc[r].x = fmaf(f.x, w0.x, acc[r].x); acc[r].y = fmaf(f.x, w0.y, acc[r].y);
            acc[r].x = fmaf(f.y, w1.x, acc[r].x); acc[r].y = fmaf(f.y, w1.y, acc[r].y);
            acc[r].x = fmaf(f.z, w2.x, acc[r].x); acc[r].y = fmaf(f.z, w2.y, acc[r].y);
            acc[r].x = fmaf(f.w, w3.x, acc[r].x); acc[r].y = fmaf(f.w, w3.y, acc[r].y);
        }
    }
    float* Pp = P + ((size_t)kc * NN + r0) * FCOLS + gc;
#pragma unroll
    for (int r = 0; r < 8; r++)
        *(float2*)(Pp + (size_t)r * FCOLS) = acc[r];
}

// ---------------------------------------------------------------------------
// K2: reduce 4 split-K partials; route to A (+bias), BT (transposed), hpre.
__global__ __launch_bounds__(256) void k_reduce(
        const float* __restrict__ P, const float* __restrict__ bfc1,
        float* __restrict__ A, float* __restrict__ BT,
        float* __restrict__ hpre) {
    int t = blockIdx.x * 256 + threadIdx.x;
    int row = t / (FCOLS / 4);
    int c4 = (t - row * (FCOLS / 4)) * 4;
    const float* p = P + (size_t)row * FCOLS + c4;
    const size_t str = (size_t)NN * FCOLS;
    float4 s0 = *(const float4*)p;
    float4 s1 = *(const float4*)(p + str);
    float4 s2 = *(const float4*)(p + 2 * str);
    float4 s3 = *(const float4*)(p + 3 * str);
    float4 s;
    s.x = (s0.x + s1.x) + (s2.x + s3.x);
    s.y = (s0.y + s1.y) + (s2.y + s3.y);
    s.z = (s0.z + s1.z) + (s2.z + s3.z);
    s.w = (s0.w + s1.w) + (s2.w + s3.w);
    if (c4 < 256) {
        float4 b = *(const float4*)(bfc1 + c4);
        s.x += b.x; s.y += b.y; s.z += b.z; s.w += b.w;
        *(float4*)(A + (size_t)row * HIDR + c4) = s;
    } else if (c4 < 512) {
        int kk = c4 - 256;
        BT[(kk + 0) * NN + row] = s.x;
        BT[(kk + 1) * NN + row] = s.y;
        BT[(kk + 2) * NN + row] = s.z;
        BT[(kk + 3) * NN + row] = s.w;
    } else {
        *(float4*)(hpre + (size_t)row * M1 + (c4 - 512)) = s;
    }
}

// ---------------------------------------------------------------------------
// K3: rel partials, split-K=4. relp[kc][i][j] = sum_{k in 64-chunk}
//   relu(A[i,k] + BT[k,j] + g_ij·Wg[:,k]) * W_fc2[k].  (b_fc2 dropped: a
// constant shift cannot change top-k order and rel is not an output.)
// grid (256, 4), block 256.
__global__ __launch_bounds__(256) void k_rel4(
        const float* __restrict__ A, const float* __restrict__ BT,
        const float* __restrict__ boxes, const float* __restrict__ Wfc1,
        const float* __restrict__ Wfc2, float* __restrict__ relp) {
    __shared__ float As[KRC], w2s[KRC], wg0[KRC], wg1[KRC], wg2[KRC], wg3[KRC];
    int i = blockIdx.x, kc = blockIdx.y, k0 = kc * KRC;
    int j = threadIdx.x;
    if (j < KRC) {
        As[j]  = A[i * HIDR + k0 + j];
        w2s[j] = Wfc2[k0 + j];
        wg0[j] = Wfc1[(size_t)(2 * FEAT + 0) * HIDR + k0 + j];
        wg1[j] = Wfc1[(size_t)(2 * FEAT + 1) * HIDR + k0 + j];
        wg2[j] = Wfc1[(size_t)(2 * FEAT + 2) * HIDR + k0 + j];
        wg3[j] = Wfc1[(size_t)(2 * FEAT + 3) * HIDR + k0 + j];
    }
    float bi0 = boxes[i * 4 + 0], bi1 = boxes[i * 4 + 1];
    float bi2 = boxes[i * 4 + 2], bi3 = boxes[i * 4 + 3];
    __syncthreads();
    float g0 = fabsf(bi0 - boxes[j * 4 + 0]);
    float g1 = fabsf(bi1 - boxes[j * 4 + 1]);
    float g2 = fabsf(bi2 - boxes[j * 4 + 2]);
    float g3 = fabsf(bi3 - boxes[j * 4 + 3]);
    const float* pB = BT + (size_t)k0 * NN + j;
    float acc = 0.f;
    for (int kk = 0; kk < KRC; kk += 4) {
        float4 a4 = *(const float4*)&As[kk];
        float4 w4 = *(const float4*)&w2s[kk];
        float4 q0 = *(const float4*)&wg0[kk];
        float4 q1 = *(const float4*)&wg1[kk];
        float4 q2 = *(const float4*)&wg2[kk];
        float4 q3 = *(const float4*)&wg3[kk];
        float b0 = pB[0], b1 = pB[NN], b2 = pB[2 * NN], b3 = pB[3 * NN];
        pB += 4 * NN;
        float v;
        v = a4.x + b0; v = fmaf(g0, q0.x, v); v = fmaf(g1, q1.x, v);
        v = fmaf(g2, q2.x, v); v = fmaf(g3, q3.x, v);
        acc = fmaf(fmaxf(v, 0.f), w4.x, acc);
        v = a4.y + b1; v = fmaf(g0, q0.y, v); v = fmaf(g1, q1.y, v);
        v = fmaf(g2, q2.y, v); v = fmaf(g3, q3.y, v);
        acc = fmaf(fmaxf(v, 0.f), w4.y, acc);
        v = a4.z + b2; v = fmaf(g0, q0.z, v); v = fmaf(g1, q1.z, v);
        v = fmaf(g2, q2.z, v); v = fmaf(g3, q3.z, v);
        acc = fmaf(fmaxf(v, 0.f), w4.z, acc);
        v = a4.w + b3; v = fmaf(g0, q0.w, v); v = fmaf(g1, q1.w, v);
        v = fmaf(g2, q2.w, v); v = fmaf(g3, q3.w, v);
        acc = fmaf(fmaxf(v, 0.f), w4.w, acc);
    }
    relp[((size_t)kc * NN + i) * NN + j] = acc;
}

// ---------------------------------------------------------------------------
// K4: parallel per-row top-4. grid 256 (row i), block 256 (col j).
// 4 rounds of block argmax on packed key (orderedFloat<<32 | (255-j)):
// max key == max value, lowest index on ties (matches jax.lax.top_k).
// Rank 0 dropped, ranks 1..3 -> idxTop. Also writes geomn.
__global__ __launch_bounds__(256) void k_topk(
        const float* __restrict__ relp, const float* __restrict__ boxes,
        const int* __restrict__ imh, const int* __restrict__ imw,
        int* __restrict__ idxTop, float* __restrict__ geomn) {
    __shared__ float sval[NN];
    __shared__ unsigned long long swk[4];
    __shared__ int win;
    int i = blockIdx.x, j = threadIdx.x;
    float v = (relp[(size_t)i * NN + j] + relp[(size_t)(NN + i) * NN + j])
            + (relp[(size_t)(2 * NN + i) * NN + j] + relp[(size_t)(3 * NN + i) * NN + j]);
    sval[j] = v;
    if (j == 0) {
        float w = (float)imw[0], h = (float)imh[0];
        float x1 = boxes[i * 4 + 0] / w, y1 = boxes[i * 4 + 1] / h;
        float x2 = boxes[i * 4 + 2] / w, y2 = boxes[i * 4 + 3] / h;
        geomn[i * 4 + 0] = x1;
        geomn[i * 4 + 1] = y1;
        geomn[i * 4 + 2] = x2 - x1;
        geomn[i * 4 + 3] = y2 - y1;
    }
    __syncthreads();
    for (int r = 0; r < 4; r++) {
        float x = sval[j];
        unsigned u = __float_as_uint(x);
        u = (u & 0x80000000u) ? ~u : (u | 0x80000000u);
        unsigned long long key =
            ((unsigned long long)u << 32) | (unsigned)(NN - 1 - j);
#pragma unroll
        for (int o = 32; o > 0; o >>= 1) {
            unsigned long long nk = __shfl_down(key, o);
            if (nk > key) key = nk;
        }
        if ((j & 63) == 0) swk[j >> 6] = key;
        __syncthreads();
        if (j == 0) {
            unsigned long long m = swk[0];
            if (swk[1] > m) m = swk[1];
            if (swk[2] > m) m = swk[2];
            if (swk[3] > m) m = swk[3];
            int wj = NN - 1 - (int)(m & 0xFFFFFFFFu);
            win = wj;
            if (r > 0) idxTop[i * 3 + (r - 1)] = wj;
        }
        __syncthreads();
        if (j == win) sval[j] = -1e38f;
        __syncthreads();
    }
}

// ---------------------------------------------------------------------------
// K5: deterministic incoming-edge lists. grid 256 (target t), block 256
// (source i). Flag membership, LDS prefix-sum for ascending slots (no
// atomics -> replay-deterministic), append self loop.
__global__ __launch_bounds__(256) void k_build(
        const int* __restrict__ idxTop, int* __restrict__ deg,
        int* __restrict__ inlist) {
    __shared__ int pfx[NN];
    int t = blockIdx.x, i = threadIdx.x;
    int f = (idxTop[i * 3 + 0] == t) | (idxTop[i * 3 + 1] == t)
          | (idxTop[i * 3 + 2] == t);   // row's topk entries are distinct
    pfx[i] = f;
    __syncthreads();
    for (int o = 1; o < NN; o <<= 1) {
        int add = (i >= o) ? pfx[i - o] : 0;
        __syncthreads();
        pfx[i] += add;
        __syncthreads();
    }
    if (f) inlist[t * MAXDEG + (pfx[i] - 1)] = i;
    if (i == NN - 1) {
        int d = pfx[NN - 1];
        inlist[t * MAXDEG + d] = t;   // GATConv self loop
        deg[t] = d + 1;
    }
}

// ---------------------------------------------------------------------------
// K6: add geomn contribution to hpre (deferred W1 rows 1024..1027) and
// compute per-node, per-head attention dots es1/ed1. grid 256, block 256.
__global__ __launch_bounds__(256) void k_fixscore(
        float* __restrict__ hpre, const float* __restrict__ geomn,
        const float* __restrict__ W1, const float* __restrict__ as1,
        const float* __restrict__ ad1, float* __restrict__ es1,
        float* __restrict__ ed1) {
    int n = blockIdx.x, tid = threadIdx.x;
    int c = tid * 4;
    float g0 = geomn[n * 4 + 0], g1 = geomn[n * 4 + 1];
    float g2 = geomn[n * 4 + 2], g3 = geomn[n * 4 + 3];
    float4 hx = *(const float4*)(hpre + (size_t)n * M1 + c);
    float4 wv;
    wv = *(const float4*)(W1 + (size_t)(FEAT + 0) * M1 + c);
    hx.x = fmaf(g0, wv.x, hx.x); hx.y = fmaf(g0, wv.y, hx.y);
    hx.z = fmaf(g0, wv.z, hx.z); hx.w = fmaf(g0, wv.w, hx.w);
    wv = *(const float4*)(W1 + (size_t)(FEAT + 1) * M1 + c);
    hx.x = fmaf(g1, wv.x, hx.x); hx.y = fmaf(g1, wv.y, hx.y);
    hx.z = fmaf(g1, wv.z, hx.z); hx.w = fmaf(g1, wv.w, hx.w);
    wv = *(const float4*)(W1 + (size_t)(FEAT + 2) * M1 + c);
    hx.x = fmaf(g2, wv.x, hx.x); hx.y = fmaf(g2, wv.y, hx.y);
    hx.z = fmaf(g2, wv.z, hx.z); hx.w = fmaf(g2, wv.w, hx.w);
    wv = *(const float4*)(W1 + (size_t)(FEAT + 3) * M1 + c);
    hx.x = fmaf(g3, wv.x, hx.x); hx.y = fmaf(g3, wv.y, hx.y);
    hx.z = fmaf(g3, wv.z, hx.z); hx.w = fmaf(g3, wv.w, hx.w);
    *(float4*)(hpre + (size_t)n * M1 + c) = hx;
    float4 a = *(const float4*)(as1 + c);
    float4 b = *(const float4*)(ad1 + c);
    float ps = hx.x * a.x + hx.y * a.y + hx.z * a.z + hx.w * a.w;
    float pd = hx.x * b.x + hx.y * b.y + hx.z * b.z + hx.w * b.w;
#pragma unroll
    for (int o = 32; o > 0; o >>= 1) {
        ps += __shfl_down(ps, o);
        pd += __shfl_down(pd, o);
    }
    if ((tid & 63) == 0) {
        es1[n * 4 + (tid >> 6)] = ps;
        ed1[n * 4 + (tid >> 6)] = pd;
    }
}

// ---------------------------------------------------------------------------
// K7: GAT layer 1 softmax-aggregate + bias + relu. grid 256 (target t),
// block 256; thread tid owns channels {q*256+tid}.
__global__ __launch_bounds__(256) void k_gat1(
        const float* __restrict__ hpre, const float* __restrict__ es1,
        const float* __restrict__ ed1, const int* __restrict__ deg,
        const int* __restrict__ inlist, const float* __restrict__ b1,
        float* __restrict__ h1) {
    __shared__ float sc[MAXDEG * 4];
    __shared__ float mh[4], dh[4];
    int t = blockIdx.x, tid = threadIdx.x;
    int dg = deg[t];
    for (int p = tid; p < dg * 4; p += 256) {
        int e = p >> 2, h = p & 3;
        int s = inlist[t * MAXDEG + e];
        float v = es1[s * 4 + h] + ed1[t * 4 + h];
        sc[p] = v >= 0.f ? v : 0.2f * v;  // leaky_relu(0.2)
    }
    __syncthreads();
    if (tid < 4) {
        float m = -1e30f;
        for (int e = 0; e < dg; e++) m = fmaxf(m, sc[e * 4 + tid]);
        float s = 0.f;
        for (int e = 0; e < dg; e++) s += expf(sc[e * 4 + tid] - m);
        mh[tid] = m; dh[tid] = s;
    }
    __syncthreads();
    for (int p = tid; p < dg * 4; p += 256) {
        int h = p & 3;
        sc[p] = expf(sc[p] - mh[h]) / dh[h];  // alpha
    }
    __syncthreads();
    float acc[4] = {0.f, 0.f, 0.f, 0.f};
    for (int e = 0; e < dg; e++) {
        int s = inlist[t * MAXDEG + e];
        const float* hs = hpre + (size_t)s * M1;
#pragma unroll
        for (int q = 0; q < 4; q++)
            acc[q] = fmaf(sc[e * 4 + q], hs[q * GCNH + tid], acc[q]);
    }
#pragma unroll
    for (int q = 0; q < 4; q++) {
        int c = q * GCNH + tid;
        h1[(size_t)t * M1 + c] = fmaxf(acc[q] + b1[c], 0.f);
    }
}

// ---------------------------------------------------------------------------
// K8: h2 = h1 @ W2 (1024 -> 21) + es2/ed2 dots. grid 256, block 256.
__global__ __launch_bounds__(256) void k_h2(
        const float* __restrict__ h1, const float* __restrict__ W2,
        const float* __restrict__ as2, const float* __restrict__ ad2,
        float* __restrict__ h2, float* __restrict__ es2,
        float* __restrict__ ed2) {
    __shared__ float sh[M1];
    __shared__ float part[12 * OUTC];
    __shared__ float h2row[OUTC];
    int n = blockIdx.x, tid = threadIdx.x;
    *(float4*)&sh[tid * 4] = *(const float4*)(h1 + (size_t)n * M1 + tid * 4);
    __syncthreads();
    if (tid < 252) {
        int o = tid % OUTC, p = tid / OUTC;
        float acc = 0.f;
        for (int d = p; d < M1; d += 12)
            acc = fmaf(sh[d], W2[d * OUTC + o], acc);
        part[p * OUTC + o] = acc;
    }
    __syncthreads();
    if (tid < OUTC) {
        float s = 0.f;
        for (int p = 0; p < 12; p++) s += part[p * OUTC + tid];
        h2[n * OUTC + tid] = s;
        h2row[tid] = s;
    }
    __syncthreads();
    if (tid == 0) {
        float s = 0.f, dd = 0.f;
        for (int k = 0; k < OUTC; k++) {
            s = fmaf(h2row[k], as2[k], s);
            dd = fmaf(h2row[k], ad2[k], dd);
        }
        es2[n] = s; ed2[n] = dd;
    }
}

// ---------------------------------------------------------------------------
// K9: GAT layer 2 softmax-aggregate + bias -> logits; argmax -> labels.
// grid 256 (target t), block 64. out = [logits (256x21) | labels (256) as f32]
__global__ __launch_bounds__(64) void k_gat2(
        const float* __restrict__ h2, const float* __restrict__ es2,
        const float* __restrict__ ed2, const int* __restrict__ deg,
        const int* __restrict__ inlist, const float* __restrict__ b2,
        float* __restrict__ out) {
    __shared__ float sc[MAXDEG];
    __shared__ float md[2];
    __shared__ float lv[OUTC];
    int t = blockIdx.x, tid = threadIdx.x;
    int dg = deg[t];
    float edt = ed2[t];
    for (int p = tid; p < dg; p += 64) {
        int s = inlist[t * MAXDEG + p];
        float v = es2[s] + edt;
        sc[p] = v >= 0.f ? v : 0.2f * v;
    }
    __syncthreads();
    if (tid == 0) {
        float m = -1e30f;
        for (int e = 0; e < dg; e++) m = fmaxf(m, sc[e]);
        float s = 0.f;
        for (int e = 0; e < dg; e++) s += expf(sc[e] - m);
        md[0] = m; md[1] = s;
    }
    __syncthreads();
    if (tid < OUTC) {
        float acc = 0.f;
        for (int e = 0; e < dg; e++) {
            int s = inlist[t * MAXDEG + e];
            float a = expf(sc[e] - md[0]) / md[1];
            acc = fmaf(a, h2[s * OUTC + tid], acc);
        }
        float v = acc + b2[tid];
        out[t * OUTC + tid] = v;
        lv[tid] = v;
    }
    __syncthreads();
    if (tid == 0) {
        int best = 0;
        float bv = lv[0];
        for (int o = 1; o < OUTC; o++)
            if (lv[o] > bv) { bv = lv[o]; best = o; }  // first max wins
        out[NN * OUTC + t] = (float)best;
    }
}

// ---------------------------------------------------------------------------
extern "C" void kernel_launch(void* const* d_in, const int* in_sizes, int n_in,
                              void* d_out, int out_size, void* d_ws,
                              size_t ws_size, hipStream_t stream) {
    const float* feat  = (const float*)d_in[0];
    const float* boxes = (const float*)d_in[1];
    const float* Wfc1  = (const float*)d_in[2];
    const float* bfc1  = (const float*)d_in[3];
    const float* Wfc2  = (const float*)d_in[4];
    const float* bfc2  = (const float*)d_in[5];   (void)bfc2;
    const float* W1    = (const float*)d_in[6];
    const float* as1   = (const float*)d_in[7];
    const float* ad1   = (const float*)d_in[8];
    const float* b1    = (const float*)d_in[9];
    const float* W2    = (const float*)d_in[10];
    const float* as2   = (const float*)d_in[11];
    const float* ad2   = (const float*)d_in[12];
    const float* b2    = (const float*)d_in[13];
    const int*   imh   = (const int*)d_in[14];
    const int*   imw   = (const int*)d_in[15];

    float* ws = (float*)d_ws;
    float* P     = ws;  ws += KC * NN * FCOLS;   // 1,572,864 floats
    float* A     = ws;  ws += NN * HIDR;
    float* BT    = ws;  ws += NN * HIDR;
    float* hpre  = ws;  ws += NN * M1;
    float* h1    = ws;  ws += NN * M1;
    float* es1   = ws;  ws += NN * 4;
    float* ed1   = ws;  ws += NN * 4;
    float* h2    = ws;  ws += NN * OUTC;
    float* es2   = ws;  ws += NN;
    float* ed2   = ws;  ws += NN;
    float* geomn = ws;  ws += NN * 4;
    int* deg     = (int*)ws;
    int* inlist  = deg + NN;
    int* idxTop  = inlist + NN * MAXDEG;
    // relp aliases P: P is fully consumed by k_reduce before k_rel4 writes it.
    float* relp  = P;

    float* out = (float*)d_out;

    k_big<<<dim3(32, 3, KC), 256, 0, stream>>>(feat, Wfc1, W1, P);
    k_reduce<<<384, 256, 0, stream>>>(P, bfc1, A, BT, hpre);
    k_rel4<<<dim3(NN, KR), 256, 0, stream>>>(A, BT, boxes, Wfc1, Wfc2, relp);
    k_topk<<<NN, 256, 0, stream>>>(relp, boxes, imh, imw, idxTop, geomn);
    k_build<<<NN, 256, 0, stream>>>(idxTop, deg, inlist);
    k_fixscore<<<NN, 256, 0, stream>>>(hpre, geomn, W1, as1, ad1, es1, ed1);
    k_gat1<<<NN, 256, 0, stream>>>(hpre, es1, ed1, deg, inlist, b1, h1);
    k_h2<<<NN, 256, 0, stream>>>(h1, W2, as2, ad2, h2, es2, ed2);
    k_gat2<<<NN, 64, 0, stream>>>(h2, es2, ed2, deg, inlist, b2, out);
}

// Round 4
// 163.364 us; speedup vs baseline: 2.2586x; 1.1505x over previous
//
#include <hip/hip_runtime.h>
#include <math.h>

#define NN 256
#define FEAT 1024
#define HIDR 256
#define HEADS 4
#define GCNH 256
#define M1 1024            // HEADS*GCNH
#define OUTC 21
#define MAXDEG (NN + 1)    // up to 256 topk-incoming + 1 self loop
#define KC 8               // split-K factor for the fused GEMM
#define KCH (FEAT / KC)    // 128
#define FCOLS 1536         // fused output cols: A(256) | B(256) | hpre(1024)

// ---------------------------------------------------------------------------
// K1: fused split-K GEMM. Output cols [0,256)=A pre-bias, [256,512)=B,
// [512,1536)=feat@W1[:1024] (hpre without the geom rows, fixed in k_redfix).
// grid (32 row-groups, 3 col-groups of 512, 8 K-chunks), block 256.
__global__ __launch_bounds__(256) void k_big(
        const float* __restrict__ feat, const float* __restrict__ Wfc1,
        const float* __restrict__ W1, float* __restrict__ P) {
    __shared__ float fS[8][KCH];
    int rg = blockIdx.x, cg = blockIdx.y, kc = blockIdx.z;
    int tid = threadIdx.x;
    int r0 = rg * 8, k0 = kc * KCH;
    for (int x = tid; x < 8 * KCH; x += 256) {
        int r = x >> 7, kk = x & (KCH - 1);
        fS[r][kk] = feat[(size_t)(r0 + r) * FEAT + k0 + kk];
    }
    __syncthreads();
    int gc = cg * 512 + tid * 2;
    const float* pW;
    int ld;
    if (gc < 256)      { pW = Wfc1 + (size_t)k0 * HIDR + gc;                  ld = HIDR; }
    else if (gc < 512) { pW = Wfc1 + (size_t)(FEAT + k0) * HIDR + (gc - 256); ld = HIDR; }
    else               { pW = W1   + (size_t)k0 * M1 + (gc - 512);            ld = M1;   }
    float2 acc[8];
#pragma unroll
    for (int r = 0; r < 8; r++) { acc[r].x = 0.f; acc[r].y = 0.f; }
    for (int kk = 0; kk < KCH; kk += 4) {
        float2 w0 = *(const float2*)(pW);
        float2 w1 = *(const float2*)(pW + ld);
        float2 w2 = *(const float2*)(pW + 2 * ld);
        float2 w3 = *(const float2*)(pW + 3 * ld);
        pW += 4 * ld;
#pragma unroll
        for (int r = 0; r < 8; r++) {
            float4 f = *(const float4*)&fS[r][kk];
            acc[r].x = fmaf(f.x, w0.x, acc[r].x); acc[r].y = fmaf(f.x, w0.y, acc[r].y);
            acc[r].x = fmaf(f.y, w1.x, acc[r].x); acc[r].y = fmaf(f.y, w1.y, acc[r].y);
            acc[r].x = fmaf(f.z, w2.x, acc[r].x); acc[r].y = fmaf(f.z, w2.y, acc[r].y);
            acc[r].x = fmaf(f.w, w3.x, acc[r].x); acc[r].y = fmaf(f.w, w3.y, acc[r].y);
        }
    }
    float* Pp = P + ((size_t)kc * NN + r0) * FCOLS + gc;
#pragma unroll
    for (int r = 0; r < 8; r++)
        *(float2*)(Pp + (size_t)r * FCOLS) = acc[r];
}

// ---------------------------------------------------------------------------
// K2: reduce 8 split-K partials + route + geom fixup + attention dots.
// grid 256 (row), block 384 (one float4 of the 1536 fused cols per thread).
// Wave 0 -> A (+bias); wave 1 -> BT (transposed); waves 2..5 -> hpre head
// (w-2): add geom rows of W1, store, and shuffle-reduce es1/ed1 dots.
// Also writes geomn (needs only boxes).
__global__ __launch_bounds__(384) void k_redfix(
        const float* __restrict__ P, const float* __restrict__ bfc1,
        const float* __restrict__ boxes, const int* __restrict__ imh,
        const int* __restrict__ imw, const float* __restrict__ W1,
        const float* __restrict__ as1, const float* __restrict__ ad1,
        float* __restrict__ A, float* __restrict__ BT,
        float* __restrict__ hpre, float* __restrict__ es1,
        float* __restrict__ ed1, float* __restrict__ geomn) {
    __shared__ float gS[4];
    int row = blockIdx.x, tid = threadIdx.x;
    int c4 = tid * 4;
    const float* p = P + (size_t)row * FCOLS + c4;
    const size_t str = (size_t)NN * FCOLS;
    float4 t0 = *(const float4*)(p);
    float4 t1 = *(const float4*)(p + str);
    float4 t2 = *(const float4*)(p + 2 * str);
    float4 t3 = *(const float4*)(p + 3 * str);
    float4 t4 = *(const float4*)(p + 4 * str);
    float4 t5 = *(const float4*)(p + 5 * str);
    float4 t6 = *(const float4*)(p + 6 * str);
    float4 t7 = *(const float4*)(p + 7 * str);
    float4 s;
    s.x = ((t0.x + t1.x) + (t2.x + t3.x)) + ((t4.x + t5.x) + (t6.x + t7.x));
    s.y = ((t0.y + t1.y) + (t2.y + t3.y)) + ((t4.y + t5.y) + (t6.y + t7.y));
    s.z = ((t0.z + t1.z) + (t2.z + t3.z)) + ((t4.z + t5.z) + (t6.z + t7.z));
    s.w = ((t0.w + t1.w) + (t2.w + t3.w)) + ((t4.w + t5.w) + (t6.w + t7.w));
    if (tid == 0) {
        float w = (float)imw[0], h = (float)imh[0];
        float x1 = boxes[row * 4 + 0] / w, y1 = boxes[row * 4 + 1] / h;
        float x2 = boxes[row * 4 + 2] / w, y2 = boxes[row * 4 + 3] / h;
        gS[0] = x1; gS[1] = y1; gS[2] = x2 - x1; gS[3] = y2 - y1;
        geomn[row * 4 + 0] = x1;
        geomn[row * 4 + 1] = y1;
        geomn[row * 4 + 2] = x2 - x1;
        geomn[row * 4 + 3] = y2 - y1;
    }
    __syncthreads();
    if (c4 < 256) {
        float4 b = *(const float4*)(bfc1 + c4);
        s.x += b.x; s.y += b.y; s.z += b.z; s.w += b.w;
        *(float4*)(A + (size_t)row * HIDR + c4) = s;
    } else if (c4 < 512) {
        int kk = c4 - 256;
        BT[(kk + 0) * NN + row] = s.x;
        BT[(kk + 1) * NN + row] = s.y;
        BT[(kk + 2) * NN + row] = s.z;
        BT[(kk + 3) * NN + row] = s.w;
    } else {
        int ch = c4 - 512;
        float g0 = gS[0], g1 = gS[1], g2 = gS[2], g3 = gS[3];
        float4 wv;
        wv = *(const float4*)(W1 + (size_t)(FEAT + 0) * M1 + ch);
        s.x = fmaf(g0, wv.x, s.x); s.y = fmaf(g0, wv.y, s.y);
        s.z = fmaf(g0, wv.z, s.z); s.w = fmaf(g0, wv.w, s.w);
        wv = *(const float4*)(W1 + (size_t)(FEAT + 1) * M1 + ch);
        s.x = fmaf(g1, wv.x, s.x); s.y = fmaf(g1, wv.y, s.y);
        s.z = fmaf(g1, wv.z, s.z); s.w = fmaf(g1, wv.w, s.w);
        wv = *(const float4*)(W1 + (size_t)(FEAT + 2) * M1 + ch);
        s.x = fmaf(g2, wv.x, s.x); s.y = fmaf(g2, wv.y, s.y);
        s.z = fmaf(g2, wv.z, s.z); s.w = fmaf(g2, wv.w, s.w);
        wv = *(const float4*)(W1 + (size_t)(FEAT + 3) * M1 + ch);
        s.x = fmaf(g3, wv.x, s.x); s.y = fmaf(g3, wv.y, s.y);
        s.z = fmaf(g3, wv.z, s.z); s.w = fmaf(g3, wv.w, s.w);
        *(float4*)(hpre + (size_t)row * M1 + ch) = s;
        float4 a = *(const float4*)(as1 + ch);
        float4 b = *(const float4*)(ad1 + ch);
        float ps = s.x * a.x + s.y * a.y + s.z * a.z + s.w * a.w;
        float pd = s.x * b.x + s.y * b.y + s.z * b.z + s.w * b.w;
#pragma unroll
        for (int o = 32; o > 0; o >>= 1) {
            ps += __shfl_down(ps, o);
            pd += __shfl_down(pd, o);
        }
        if ((tid & 63) == 0) {
            int head = (tid - 128) >> 6;
            es1[row * 4 + head] = ps;
            ed1[row * 4 + head] = pd;
        }
    }
}

// ---------------------------------------------------------------------------
// K3: fused rel-row + top-k. grid 256 (row i), block 512: thread (j, half)
// computes the K-half of rel[i][j] = sum_k relu(A[i,k]+BT[k,j]+g.Wg[:,k])
// *W_fc2[k]; halves combined in LDS; then 4 rounds of block argmax on packed
// key (orderedFloat<<32 | (255-j)) -> rank 1..3 indices (matches
// jax.lax.top_k stable order). rel is never materialized in global memory.
// (b_fc2 dropped: a constant shift cannot change top-k order.)
__global__ __launch_bounds__(512) void k_reltopk(
        const float* __restrict__ A, const float* __restrict__ BT,
        const float* __restrict__ boxes, const float* __restrict__ Wfc1,
        const float* __restrict__ Wfc2, int* __restrict__ idxTop) {
    __shared__ float As[HIDR], w2s[HIDR], wg0[HIDR], wg1[HIDR], wg2[HIDR], wg3[HIDR];
    __shared__ float sval[512];
    __shared__ unsigned long long swk[8];
    __shared__ int win;
    int i = blockIdx.x, tid = threadIdx.x;
    int j = tid & 255, half = tid >> 8;
    if (tid < 256) {
        As[tid]  = A[i * HIDR + tid];
        w2s[tid] = Wfc2[tid];
        wg0[tid] = Wfc1[(size_t)(2 * FEAT + 0) * HIDR + tid];
    } else {
        int q = tid - 256;
        wg1[q] = Wfc1[(size_t)(2 * FEAT + 1) * HIDR + q];
        wg2[q] = Wfc1[(size_t)(2 * FEAT + 2) * HIDR + q];
        wg3[q] = Wfc1[(size_t)(2 * FEAT + 3) * HIDR + q];
    }
    float bi0 = boxes[i * 4 + 0], bi1 = boxes[i * 4 + 1];
    float bi2 = boxes[i * 4 + 2], bi3 = boxes[i * 4 + 3];
    float g0 = fabsf(bi0 - boxes[j * 4 + 0]);
    float g1 = fabsf(bi1 - boxes[j * 4 + 1]);
    float g2 = fabsf(bi2 - boxes[j * 4 + 2]);
    float g3 = fabsf(bi3 - boxes[j * 4 + 3]);
    __syncthreads();
    int k0 = half * 128;
    const float* pB = BT + (size_t)k0 * NN + j;
    float acc = 0.f;
    for (int kk = k0; kk < k0 + 128; kk += 4) {
        float4 a4 = *(const float4*)&As[kk];
        float4 w4 = *(const float4*)&w2s[kk];
        float4 q0 = *(const float4*)&wg0[kk];
        float4 q1 = *(const float4*)&wg1[kk];
        float4 q2 = *(const float4*)&wg2[kk];
        float4 q3 = *(const float4*)&wg3[kk];
        float b0 = pB[0], b1 = pB[NN], b2 = pB[2 * NN], b3 = pB[3 * NN];
        pB += 4 * NN;
        float v;
        v = a4.x + b0; v = fmaf(g0, q0.x, v); v = fmaf(g1, q1.x, v);
        v = fmaf(g2, q2.x, v); v = fmaf(g3, q3.x, v);
        acc = fmaf(fmaxf(v, 0.f), w4.x, acc);
        v = a4.y + b1; v = fmaf(g0, q0.y, v); v = fmaf(g1, q1.y, v);
        v = fmaf(g2, q2.y, v); v = fmaf(g3, q3.y, v);
        acc = fmaf(fmaxf(v, 0.f), w4.y, acc);
        v = a4.z + b2; v = fmaf(g0, q0.z, v); v = fmaf(g1, q1.z, v);
        v = fmaf(g2, q2.z, v); v = fmaf(g3, q3.z, v);
        acc = fmaf(fmaxf(v, 0.f), w4.z, acc);
        v = a4.w + b3; v = fmaf(g0, q0.w, v); v = fmaf(g1, q1.w, v);
        v = fmaf(g2, q2.w, v); v = fmaf(g3, q3.w, v);
        acc = fmaf(fmaxf(v, 0.f), w4.w, acc);
    }
    sval[tid] = acc;
    __syncthreads();
    if (tid < 256) sval[tid] = sval[tid] + sval[tid + 256];
    __syncthreads();
    for (int r = 0; r < 4; r++) {
        unsigned long long key = 0ULL;
        if (tid < 256) {
            unsigned u = __float_as_uint(sval[tid]);
            u = (u & 0x80000000u) ? ~u : (u | 0x80000000u);
            key = ((unsigned long long)u << 32) | (unsigned)(NN - 1 - tid);
        }
#pragma unroll
        for (int o = 32; o > 0; o >>= 1) {
            unsigned long long nk = __shfl_down(key, o);
            if (nk > key) key = nk;
        }
        if ((tid & 63) == 0) swk[tid >> 6] = key;
        __syncthreads();
        if (tid == 0) {
            unsigned long long m = swk[0];
#pragma unroll
            for (int q = 1; q < 8; q++) if (swk[q] > m) m = swk[q];
            int wj = NN - 1 - (int)(m & 0xFFFFFFFFu);
            win = wj;
            if (r > 0) idxTop[i * 3 + (r - 1)] = wj;
        }
        __syncthreads();
        if (tid == win) sval[tid] = -1e38f;
        __syncthreads();
    }
}

// ---------------------------------------------------------------------------
// K4: deterministic incoming-edge lists. grid 256 (target t), block 256
// (source i). Flag membership, LDS prefix-sum for ascending slots (no
// atomics -> replay-deterministic), append self loop.
__global__ __launch_bounds__(256) void k_build(
        const int* __restrict__ idxTop, int* __restrict__ deg,
        int* __restrict__ inlist) {
    __shared__ int pfx[NN];
    int t = blockIdx.x, i = threadIdx.x;
    int f = (idxTop[i * 3 + 0] == t) | (idxTop[i * 3 + 1] == t)
          | (idxTop[i * 3 + 2] == t);   // row's topk entries are distinct
    pfx[i] = f;
    __syncthreads();
    for (int o = 1; o < NN; o <<= 1) {
        int add = (i >= o) ? pfx[i - o] : 0;
        __syncthreads();
        pfx[i] += add;
        __syncthreads();
    }
    if (f) inlist[t * MAXDEG + (pfx[i] - 1)] = i;
    if (i == NN - 1) {
        int d = pfx[NN - 1];
        inlist[t * MAXDEG + d] = t;   // GATConv self loop
        deg[t] = d + 1;
    }
}

// ---------------------------------------------------------------------------
// K5: fused GAT-1 aggregate (+bias+relu, h1 kept in LDS) and h2 = h1@W2
// (1024->21) + es2/ed2 dots. grid 256 (target t), block 256. h1 never
// touches global memory.
__global__ __launch_bounds__(256) void k_gat1h2(
        const float* __restrict__ hpre, const float* __restrict__ es1,
        const float* __restrict__ ed1, const int* __restrict__ deg,
        const int* __restrict__ inlist, const float* __restrict__ b1,
        const float* __restrict__ W2, const float* __restrict__ as2,
        const float* __restrict__ ad2, float* __restrict__ h2,
        float* __restrict__ es2, float* __restrict__ ed2) {
    __shared__ float sc[MAXDEG * 4];
    __shared__ float mh[4], dh[4];
    __shared__ float sh[M1];
    __shared__ float part[12 * OUTC];
    __shared__ float h2row[OUTC];
    int t = blockIdx.x, tid = threadIdx.x;
    int dg = deg[t];
    for (int p = tid; p < dg * 4; p += 256) {
        int e = p >> 2, h = p & 3;
        int s = inlist[t * MAXDEG + e];
        float v = es1[s * 4 + h] + ed1[t * 4 + h];
        sc[p] = v >= 0.f ? v : 0.2f * v;  // leaky_relu(0.2)
    }
    __syncthreads();
    if (tid < 4) {
        float m = -1e30f;
        for (int e = 0; e < dg; e++) m = fmaxf(m, sc[e * 4 + tid]);
        float s = 0.f;
        for (int e = 0; e < dg; e++) s += expf(sc[e * 4 + tid] - m);
        mh[tid] = m; dh[tid] = s;
    }
    __syncthreads();
    for (int p = tid; p < dg * 4; p += 256) {
        int h = p & 3;
        sc[p] = expf(sc[p] - mh[h]) / dh[h];  // alpha
    }
    __syncthreads();
    float acc[4] = {0.f, 0.f, 0.f, 0.f};
    for (int e = 0; e < dg; e++) {
        int s = inlist[t * MAXDEG + e];
        const float* hs = hpre + (size_t)s * M1;
#pragma unroll
        for (int q = 0; q < 4; q++)
            acc[q] = fmaf(sc[e * 4 + q], hs[q * GCNH + tid], acc[q]);
    }
#pragma unroll
    for (int q = 0; q < 4; q++) {
        int c = q * GCNH + tid;
        sh[c] = fmaxf(acc[q] + b1[c], 0.f);   // h1 row, LDS only
    }
    __syncthreads();
    if (tid < 252) {
        int o = tid % OUTC, p = tid / OUTC;
        float a2 = 0.f;
        for (int d = p; d < M1; d += 12)
            a2 = fmaf(sh[d], W2[d * OUTC + o], a2);
        part[p * OUTC + o] = a2;
    }
    __syncthreads();
    if (tid < OUTC) {
        float s = 0.f;
        for (int p = 0; p < 12; p++) s += part[p * OUTC + tid];
        h2[t * OUTC + tid] = s;
        h2row[tid] = s;
    }
    __syncthreads();
    if (tid == 0) {
        float s = 0.f, dd = 0.f;
        for (int k = 0; k < OUTC; k++) {
            s = fmaf(h2row[k], as2[k], s);
            dd = fmaf(h2row[k], ad2[k], dd);
        }
        es2[t] = s; ed2[t] = dd;
    }
}

// ---------------------------------------------------------------------------
// K6: GAT layer 2 softmax-aggregate + bias -> logits; argmax -> labels.
// grid 256 (target t), block 64. out = [logits (256x21) | labels (256) as f32]
__global__ __launch_bounds__(64) void k_gat2(
        const float* __restrict__ h2, const float* __restrict__ es2,
        const float* __restrict__ ed2, const int* __restrict__ deg,
        const int* __restrict__ inlist, const float* __restrict__ b2,
        float* __restrict__ out) {
    __shared__ float sc[MAXDEG];
    __shared__ float md[2];
    __shared__ float lv[OUTC];
    int t = blockIdx.x, tid = threadIdx.x;
    int dg = deg[t];
    float edt = ed2[t];
    for (int p = tid; p < dg; p += 64) {
        int s = inlist[t * MAXDEG + p];
        float v = es2[s] + edt;
        sc[p] = v >= 0.f ? v : 0.2f * v;
    }
    __syncthreads();
    if (tid == 0) {
        float m = -1e30f;
        for (int e = 0; e < dg; e++) m = fmaxf(m, sc[e]);
        float s = 0.f;
        for (int e = 0; e < dg; e++) s += expf(sc[e] - m);
        md[0] = m; md[1] = s;
    }
    __syncthreads();
    if (tid < OUTC) {
        float acc = 0.f;
        for (int e = 0; e < dg; e++) {
            int s = inlist[t * MAXDEG + e];
            float a = expf(sc[e] - md[0]) / md[1];
            acc = fmaf(a, h2[s * OUTC + tid], acc);
        }
        float v = acc + b2[tid];
        out[t * OUTC + tid] = v;
        lv[tid] = v;
    }
    __syncthreads();
    if (tid == 0) {
        int best = 0;
        float bv = lv[0];
        for (int o = 1; o < OUTC; o++)
            if (lv[o] > bv) { bv = lv[o]; best = o; }  // first max wins
        out[NN * OUTC + t] = (float)best;
    }
}

// ---------------------------------------------------------------------------
extern "C" void kernel_launch(void* const* d_in, const int* in_sizes, int n_in,
                              void* d_out, int out_size, void* d_ws,
                              size_t ws_size, hipStream_t stream) {
    const float* feat  = (const float*)d_in[0];
    const float* boxes = (const float*)d_in[1];
    const float* Wfc1  = (const float*)d_in[2];
    const float* bfc1  = (const float*)d_in[3];
    const float* Wfc2  = (const float*)d_in[4];
    const float* bfc2  = (const float*)d_in[5];   (void)bfc2;
    const float* W1    = (const float*)d_in[6];
    const float* as1   = (const float*)d_in[7];
    const float* ad1   = (const float*)d_in[8];
    const float* b1    = (const float*)d_in[9];
    const float* W2    = (const float*)d_in[10];
    const float* as2   = (const float*)d_in[11];
    const float* ad2   = (const float*)d_in[12];
    const float* b2    = (const float*)d_in[13];
    const int*   imh   = (const int*)d_in[14];
    const int*   imw   = (const int*)d_in[15];

    float* ws = (float*)d_ws;
    float* P     = ws;  ws += KC * NN * FCOLS;   // 3,145,728 floats
    float* A     = ws;  ws += NN * HIDR;
    float* BT    = ws;  ws += NN * HIDR;
    float* hpre  = ws;  ws += NN * M1;
    float* es1   = ws;  ws += NN * 4;
    float* ed1   = ws;  ws += NN * 4;
    float* h2    = ws;  ws += NN * OUTC;
    float* es2   = ws;  ws += NN;
    float* ed2   = ws;  ws += NN;
    float* geomn = ws;  ws += NN * 4;
    int* deg     = (int*)ws;
    int* inlist  = deg + NN;
    int* idxTop  = inlist + NN * MAXDEG;

    float* out = (float*)d_out;

    k_big<<<dim3(32, 3, KC), 256, 0, stream>>>(feat, Wfc1, W1, P);
    k_redfix<<<NN, 384, 0, stream>>>(P, bfc1, boxes, imh, imw, W1, as1, ad1,
                                     A, BT, hpre, es1, ed1, geomn);
    k_reltopk<<<NN, 512, 0, stream>>>(A, BT, boxes, Wfc1, Wfc2, idxTop);
    k_build<<<NN, 256, 0, stream>>>(idxTop, deg, inlist);
    k_gat1h2<<<NN, 256, 0, stream>>>(hpre, es1, ed1, deg, inlist, b1,
                                     W2, as2, ad2, h2, es2, ed2);
    k_gat2<<<NN, 64, 0, stream>>>(h2, es2, ed2, deg, inlist, b2, out);
}